// Round 15
// baseline (204.144 us; speedup 1.0000x reference)
//
#include <hip/hip_runtime.h>
#include <hip/hip_fp16.h>

// MinGRU stack: 3x (APL z/h + linear recurrence + maxabs-normalize) + APL out.
// B=8, T=2048, Din=D=Dout=64, P=16 knots on [-1,1].
// APL dual layers: LDS-staged, SoA-b32 slices (fixes round-5's 8-way b128
// bank conflicts), no x-tile in LDS (readlane broadcast of per-lane iv/fr),
// ONE barrier per dim, slice prefetched a full iteration ahead.
//   Rationale: rounds 7/8/9/12/14 proved the direct L2 gather is pinned at
//   ~24cy per 1KB wave-gather (42 B/cy/CU) regardless of bytes/ILP/occupancy.
//   LDS pipe is 128 B/cy/CU -> ~3x headroom for the same inner reads.
// apl_out: direct gather with f16x2 table (proven, ~11 us).
// Scan: separate pass1 / fixup / pass2 (proven). Preps separate (round-6).

#define WPB 8   // waves per block in gather-APL kernels (512 threads)
#define NC 64   // chunks per sequence
#define CL 32   // timesteps per chunk (NC*CL == T == 2048)

__device__ __forceinline__ unsigned int pack_f16(float lo, float hi) {
    return (unsigned int)__half_as_ushort(__float2half(lo))
         | ((unsigned int)__half_as_ushort(__float2half(hi)) << 16);
}
__device__ __forceinline__ float unpack_f16_lo(unsigned int u) {
    return __half2float(__ushort_as_half((unsigned short)(u & 0xffffu)));
}
__device__ __forceinline__ float unpack_f16_hi(unsigned int u) {
    return __half2float(__ushort_as_half((unsigned short)(u >> 16)));
}

// ---- table prep (all 3 dual layers): float4(z0, dz, h0, dh), f32 ----
// layout: tab[(i*15 + p)*64 + o]; slice for dim i = 960 float4s contiguous
__global__ __launch_bounds__(256) void prep_dual_kernel(
    const float* __restrict__ vz, const float* __restrict__ vh,
    float4* __restrict__ tab)
{
    int idx = blockIdx.x * blockDim.x + threadIdx.x;   // over 64*15*64
    if (idx >= 64 * 15 * 64) return;
    int o = idx & 63;
    int p = (idx >> 6) % 15;
    int i = idx / (15 * 64);
    int base = (i * 16 + p) * 64 + o;
    float z0 = vz[base], z1 = vz[base + 64];
    float h0 = vh[base], h1 = vh[base + 64];
    tab[idx] = make_float4(z0, z1 - z0, h0, h1 - h0);
}

// output table: packed f16x2 (v0 low, dv high)
__global__ __launch_bounds__(256) void prep_out_kernel(
    const float* __restrict__ v, unsigned int* __restrict__ tab)
{
    int idx = blockIdx.x * blockDim.x + threadIdx.x;
    if (idx >= 64 * 15 * 64) return;
    int o = idx & 63;
    int p = (idx >> 6) % 15;
    int i = idx / (15 * 64);
    int base = (i * 16 + p) * 64 + o;
    float v0 = v[base], v1 = v[base + 64];
    tab[idx] = pack_f16(v0, v1 - v0);
}

// ---- APL dual, LDS-staged ----
// Block = 512 threads = 8 waves; 64 samples/block (8 per wave).
// Lane l holds (iv, fr) of ITS dim l for its wave's 8 samples; at dim i they
// are broadcast via readlane (uniform -> row index scalar -> all 64 lanes
// read consecutive 4B from SoA arrays: conflict-free).
__global__ __launch_bounds__(512) void apl_dual_lds_kernel(
    const float* __restrict__ in, const float4* __restrict__ tab,
    float2* __restrict__ zh)
{
    __shared__ float slc[2][4][960];   // [buf][z0,dz,h0,dh][p*64+o] = 30720 B

    const int tid = threadIdx.x;
    const int lane = tid & 63;
    const int w = tid >> 6;
    const size_t nb = (size_t)blockIdx.x * 64 + (size_t)w * 8;  // wave's 8 samples

    int   iv8[8];
    float fr8[8];
#pragma unroll
    for (int s = 0; s < 8; ++s) {
        float xv = in[(nb + s) * 64 + lane];
        float tv = fminf(fmaxf(xv, -1.f), 1.f) * 7.5f + 7.5f;   // [0,15]
        int iv = (int)tv; iv = iv > 14 ? 14 : iv;
        iv8[s] = iv;
        fr8[s] = tv - (float)iv;
    }

    float accz[8], acch[8];
#pragma unroll
    for (int s = 0; s < 8; ++s) { accz[s] = 0.f; acch[s] = 0.f; }

    // prologue: prefetch slice 0 into registers
    float4 e0 = tab[tid];
    float4 e1 = make_float4(0.f, 0.f, 0.f, 0.f);
    if (tid < 448) e1 = tab[tid + 512];

#pragma unroll 2
    for (int i = 0; i < 64; ++i) {
        const int buf = i & 1;
        // write current slice (SoA; thread t -> addr t*4: conflict-free)
        slc[buf][0][tid] = e0.x; slc[buf][1][tid] = e0.y;
        slc[buf][2][tid] = e0.z; slc[buf][3][tid] = e0.w;
        if (tid < 448) {
            slc[buf][0][tid + 512] = e1.x; slc[buf][1][tid + 512] = e1.y;
            slc[buf][2][tid + 512] = e1.z; slc[buf][3][tid + 512] = e1.w;
        }
        // prefetch next slice (consumed next iter: full iter of latency hiding)
        if (i < 63) {
            const float4* src = tab + (size_t)(i + 1) * 960;
            e0 = src[tid];
            if (tid < 448) e1 = src[tid + 512];
        }
        __syncthreads();   // slice visible; prior-parity reads already fenced
        // compute dim i for this wave's 8 samples
#pragma unroll
        for (int s = 0; s < 8; ++s) {
            int idx  = __builtin_amdgcn_readlane(iv8[s], i);
            float fr = __int_as_float(
                __builtin_amdgcn_readlane(__float_as_int(fr8[s]), i));
            int r = idx * 64 + lane;   // uniform row, consecutive lanes
            float z0 = slc[buf][0][r];
            float dz = slc[buf][1][r];
            float h0 = slc[buf][2][r];
            float dh = slc[buf][3][r];
            accz[s] += fmaf(fr, dz, z0);
            acch[s] += fmaf(fr, dh, h0);
        }
    }

#pragma unroll
    for (int s = 0; s < 8; ++s) {
        float z = 1.f / (1.f + expf(-accz[s]));
        zh[(nb + s) * 64 + lane] = make_float2(z, acch[s]);
    }
}

// ---- APL (f16x2 table, output layer), direct gather, 8-deep batching ----
__global__ __launch_bounds__(512) void apl_out_kernel(
    const float* __restrict__ in, const unsigned int* __restrict__ tab,
    float* __restrict__ out, int N)
{
    const int lane = threadIdx.x & 63;
    const int n = blockIdx.x * WPB + (threadIdx.x >> 6);
    if (n >= N) return;

    float xv = in[(size_t)n * 64 + lane];
    float tv = fminf(fmaxf(xv, -1.f), 1.f) * 7.5f + 7.5f;
    int iv = (int)tv; iv = iv > 14 ? 14 : iv;
    float frv = tv - (float)iv;
    int offv = lane * 3840 + (iv << 8);   // uint rows: 256B; 15*256 per dim

    const char* tb = (const char*)tab + lane * 4;
    float acc0 = 0.f, acc1 = 0.f;
#pragma unroll
    for (int i0 = 0; i0 < 64; i0 += 8) {
        int of[8]; float fr[8]; unsigned int e[8];
#pragma unroll
        for (int j = 0; j < 8; ++j) of[j] = __shfl(offv, i0 + j, 64);
#pragma unroll
        for (int j = 0; j < 8; ++j) fr[j] = __shfl(frv, i0 + j, 64);
#pragma unroll
        for (int j = 0; j < 8; ++j) e[j] = *(const unsigned int*)(tb + of[j]);
#pragma unroll
        for (int j = 0; j < 8; j += 2) {
            acc0 += fmaf(fr[j], unpack_f16_hi(e[j]), unpack_f16_lo(e[j]));
            acc1 += fmaf(fr[j + 1], unpack_f16_hi(e[j + 1]), unpack_f16_lo(e[j + 1]));
        }
    }
    out[(size_t)n * 64 + lane] = acc0 + acc1;
}

// ---- scan pass 1: per-chunk affine summary (A, B): h_out = A*h_in + B ----
__global__ __launch_bounds__(256) void scan_pass1_kernel(
    const float2* __restrict__ zh, float2* __restrict__ chunkAB, int T)
{
    int lane = threadIdx.x & 63;
    int wid = blockIdx.x * (blockDim.x >> 6) + (threadIdx.x >> 6);  // b*NC + c
    int b = wid / NC, c = wid % NC;
    const float2* p = zh + ((size_t)b * T + (size_t)c * CL) * 64 + lane;

    float A = 1.f, Bc = 0.f;
    for (int k0 = 0; k0 < CL; k0 += 8) {
        float2 v[8];
#pragma unroll
        for (int k = 0; k < 8; ++k) v[k] = p[(size_t)(k0 + k) * 64];
#pragma unroll
        for (int k = 0; k < 8; ++k) {
            float a = 1.f - v[k].x;
            float bb = v[k].x * v[k].y;
            A *= a;
            Bc = fmaf(a, Bc, bb);
        }
    }
    chunkAB[(size_t)wid * 64 + lane] = make_float2(A, Bc);
}

// ---- scan fixup: sequential combine of NC chunk summaries per (b, d) ----
__global__ __launch_bounds__(64) void scan_fixup_kernel(
    const float2* __restrict__ chunkAB, float* __restrict__ hinit)
{
    int b = blockIdx.x;
    int d = threadIdx.x;
    const float2* p = chunkAB + (size_t)b * NC * 64 + d;
    float* o = hinit + (size_t)b * NC * 64 + d;

    float h = 0.f;  // h0 = 0
    for (int c0 = 0; c0 < NC; c0 += 8) {
        float2 ab[8];
#pragma unroll
        for (int k = 0; k < 8; ++k) ab[k] = p[(size_t)(c0 + k) * 64];
#pragma unroll
        for (int k = 0; k < 8; ++k) {
            o[(size_t)(c0 + k) * 64] = h;
            h = fmaf(ab[k].x, h, ab[k].y);
        }
    }
}

// ---- scan pass 2: replay chunk from hinit, fused maxabs-normalize ----
__global__ __launch_bounds__(256) void scan_pass2_kernel(
    const float2* __restrict__ zh, const float* __restrict__ hinit,
    float* __restrict__ out, int T)
{
    int lane = threadIdx.x & 63;
    int wid = blockIdx.x * (blockDim.x >> 6) + (threadIdx.x >> 6);  // b*NC + c
    int b = wid / NC, c = wid % NC;
    const float2* p = zh + ((size_t)b * T + (size_t)c * CL) * 64 + lane;
    float* o = out + ((size_t)b * T + (size_t)c * CL) * 64 + lane;

    float h = hinit[(size_t)wid * 64 + lane];
    for (int k0 = 0; k0 < CL; k0 += 8) {
        float2 v[8];
        float hs[8];
#pragma unroll
        for (int k = 0; k < 8; ++k) v[k] = p[(size_t)(k0 + k) * 64];
#pragma unroll
        for (int k = 0; k < 8; ++k) {
            h = fmaf(v[k].x, v[k].y - h, h);   // h += z*(hbar - h)
            hs[k] = h;
        }
#pragma unroll
        for (int k = 0; k < 8; ++k) {
            float m = fabsf(hs[k]);
            m = fmaxf(m, __shfl_xor(m, 32, 64));
            m = fmaxf(m, __shfl_xor(m, 16, 64));
            m = fmaxf(m, __shfl_xor(m, 8, 64));
            m = fmaxf(m, __shfl_xor(m, 4, 64));
            m = fmaxf(m, __shfl_xor(m, 2, 64));
            m = fmaxf(m, __shfl_xor(m, 1, 64));
            o[(size_t)(k0 + k) * 64] = hs[k] / (m + 1e-6f);
        }
    }
}

extern "C" void kernel_launch(void* const* d_in, const int* in_sizes, int n_in,
                              void* d_out, int out_size, void* d_ws, size_t ws_size,
                              hipStream_t stream) {
    const float* x    = (const float*)d_in[0];
    const float* vz0  = (const float*)d_in[1];
    const float* vh0  = (const float*)d_in[2];
    const float* vz1  = (const float*)d_in[3];
    const float* vh1  = (const float*)d_in[4];
    const float* vz2  = (const float*)d_in[5];
    const float* vh2  = (const float*)d_in[6];
    const float* vout = (const float*)d_in[7];

    const int N = in_sizes[0] / 64;   // B*T = 16384
    const int T = NC * CL;            // 2048
    const int B = N / T;              // 8

    char* ws = (char*)d_ws;
    const size_t TAB_ELEMS = (size_t)64 * 15 * 64;   // 61440
    float2* zh      = (float2*)ws;                                  // 8 MB
    float*  cur     = (float*)(ws + 8388608);                       // 4 MB
    float4* tab0    = (float4*)(ws + 12582912);                     // 960 KB
    float4* tab1    = (float4*)(ws + 13565952);                     // 960 KB
    float4* tab2    = (float4*)(ws + 14548992);                     // 960 KB
    unsigned int* tab_out = (unsigned int*)(ws + 15532032);         // 240 KB
    float2* chunkAB = (float2*)(ws + 16023552);                     // 256 KB
    float*  hinit   = (float*)(ws + 16285696);                      // 128 KB

    dim3 pblk(256), pgrd((TAB_ELEMS + 255) / 256);
    prep_dual_kernel<<<pgrd, pblk, 0, stream>>>(vz0, vh0, tab0);
    prep_dual_kernel<<<pgrd, pblk, 0, stream>>>(vz1, vh1, tab1);
    prep_dual_kernel<<<pgrd, pblk, 0, stream>>>(vz2, vh2, tab2);
    prep_out_kernel<<<pgrd, pblk, 0, stream>>>(vout, tab_out);

    dim3 lblk(512), lgrd(N / 64);            // 256 blocks of 512 threads
    dim3 ablk(64 * WPB), agrd((N + WPB - 1) / WPB);
    dim3 sblk(256), sgrd(B * NC / 4);        // 4 waves (chunks) per block

    const float4* tabs[3] = {tab0, tab1, tab2};
    const float* layer_in = x;
    for (int l = 0; l < 3; ++l) {
        apl_dual_lds_kernel<<<lgrd, lblk, 0, stream>>>(layer_in, tabs[l], zh);
        scan_pass1_kernel<<<sgrd, sblk, 0, stream>>>(zh, chunkAB, T);
        scan_fixup_kernel<<<B, 64, 0, stream>>>(chunkAB, hinit);
        scan_pass2_kernel<<<sgrd, sblk, 0, stream>>>(zh, hinit, cur, T);
        layer_in = cur;
    }
    apl_out_kernel<<<agrd, ablk, 0, stream>>>(cur, tab_out, (float*)d_out, N);
}

// Round 16
// 188.836 us; speedup vs baseline: 1.0811x; 1.0811x over previous
//
#include <hip/hip_runtime.h>
#include <hip/hip_fp16.h>

// MinGRU stack: 3x (APL z/h + linear recurrence + maxabs-normalize) + APL out.
// B=8, T=2048, Din=D=Dout=64, P=16 knots on [-1,1].
// APL dual layers: LDS-staged slices, AoS float4 rows read with ONE
// ds_read_b128 per sample-dim (85 B/cy vs 44 B/cy for 4x b32 -- round-15
// lesson: b32 LDS reads match the L2 gather rate; b128 is the 2x lever).
// readlane broadcast of per-lane iv/fr; one barrier per dim; slice
// prefetched a full iteration ahead into registers.
// apl_out: direct gather with f16x2 table (proven ~11 us).
// Scan: separate pass1 / fixup / pass2 (proven). Preps separate (round-6).

#define WPB 8   // waves per block in gather-APL kernels (512 threads)
#define NC 64   // chunks per sequence
#define CL 32   // timesteps per chunk (NC*CL == T == 2048)

__device__ __forceinline__ unsigned int pack_f16(float lo, float hi) {
    return (unsigned int)__half_as_ushort(__float2half(lo))
         | ((unsigned int)__half_as_ushort(__float2half(hi)) << 16);
}
__device__ __forceinline__ float unpack_f16_lo(unsigned int u) {
    return __half2float(__ushort_as_half((unsigned short)(u & 0xffffu)));
}
__device__ __forceinline__ float unpack_f16_hi(unsigned int u) {
    return __half2float(__ushort_as_half((unsigned short)(u >> 16)));
}

// ---- table prep (all 3 dual layers): float4(z0, dz, h0, dh), f32 ----
// layout: tab[(i*15 + p)*64 + o]; slice for dim i = 960 float4s contiguous
__global__ __launch_bounds__(256) void prep_dual_kernel(
    const float* __restrict__ vz, const float* __restrict__ vh,
    float4* __restrict__ tab)
{
    int idx = blockIdx.x * blockDim.x + threadIdx.x;   // over 64*15*64
    if (idx >= 64 * 15 * 64) return;
    int o = idx & 63;
    int p = (idx >> 6) % 15;
    int i = idx / (15 * 64);
    int base = (i * 16 + p) * 64 + o;
    float z0 = vz[base], z1 = vz[base + 64];
    float h0 = vh[base], h1 = vh[base + 64];
    tab[idx] = make_float4(z0, z1 - z0, h0, h1 - h0);
}

// output table: packed f16x2 (v0 low, dv high)
__global__ __launch_bounds__(256) void prep_out_kernel(
    const float* __restrict__ v, unsigned int* __restrict__ tab)
{
    int idx = blockIdx.x * blockDim.x + threadIdx.x;
    if (idx >= 64 * 15 * 64) return;
    int o = idx & 63;
    int p = (idx >> 6) % 15;
    int i = idx / (15 * 64);
    int base = (i * 16 + p) * 64 + o;
    float v0 = v[base], v1 = v[base + 64];
    tab[idx] = pack_f16(v0, v1 - v0);
}

// ---- APL dual, LDS-staged (AoS float4, b128 reads) ----
// Block = 512 threads = 8 waves; 64 samples/block (8 per wave).
// Lane l holds (iv, fr) of ITS dim l for its wave's 8 samples; at dim i they
// are broadcast via readlane; all 64 lanes then read one contiguous 1KB row
// (lane-consecutive float4) -> single ds_read_b128, conflict-free.
__global__ __launch_bounds__(512) void apl_dual_lds_kernel(
    const float* __restrict__ in, const float4* __restrict__ tab,
    float2* __restrict__ zh)
{
    __shared__ float4 slc[2][960];   // 30720 B double-buffered slice

    const int tid = threadIdx.x;
    const int lane = tid & 63;
    const int w = tid >> 6;
    const size_t nb = (size_t)blockIdx.x * 64 + (size_t)w * 8;  // wave's 8 samples

    int   iv8[8];
    float fr8[8];
#pragma unroll
    for (int s = 0; s < 8; ++s) {
        float xv = in[(nb + s) * 64 + lane];
        float tv = fminf(fmaxf(xv, -1.f), 1.f) * 7.5f + 7.5f;   // [0,15]
        int iv = (int)tv; iv = iv > 14 ? 14 : iv;
        iv8[s] = iv;
        fr8[s] = tv - (float)iv;
    }

    float accz[8], acch[8];
#pragma unroll
    for (int s = 0; s < 8; ++s) { accz[s] = 0.f; acch[s] = 0.f; }

    // prologue: prefetch slice 0 into registers
    float4 e0 = tab[tid];
    float4 e1 = make_float4(0.f, 0.f, 0.f, 0.f);
    if (tid < 448) e1 = tab[tid + 512];

#pragma unroll 2
    for (int i = 0; i < 64; ++i) {
        const int buf = i & 1;
        // write current slice: 2 ds_write_b128 per thread
        slc[buf][tid] = e0;
        if (tid < 448) slc[buf][tid + 512] = e1;
        // prefetch next slice (consumed next iter: full iter of latency hiding)
        if (i < 63) {
            const float4* src = tab + (size_t)(i + 1) * 960;
            e0 = src[tid];
            if (tid < 448) e1 = src[tid + 512];
        }
        __syncthreads();   // slice visible; prior-parity buffer disjoint
        // compute dim i for this wave's 8 samples: 8 ds_read_b128
#pragma unroll
        for (int s = 0; s < 8; ++s) {
            int idx  = __builtin_amdgcn_readlane(iv8[s], i);
            float fr = __int_as_float(
                __builtin_amdgcn_readlane(__float_as_int(fr8[s]), i));
            float4 e = slc[buf][idx * 64 + lane];   // contiguous 1KB row
            accz[s] += fmaf(fr, e.y, e.x);
            acch[s] += fmaf(fr, e.w, e.z);
        }
    }

#pragma unroll
    for (int s = 0; s < 8; ++s) {
        float z = 1.f / (1.f + expf(-accz[s]));
        zh[(nb + s) * 64 + lane] = make_float2(z, acch[s]);
    }
}

// ---- APL (f16x2 table, output layer), direct gather, 8-deep batching ----
__global__ __launch_bounds__(512) void apl_out_kernel(
    const float* __restrict__ in, const unsigned int* __restrict__ tab,
    float* __restrict__ out, int N)
{
    const int lane = threadIdx.x & 63;
    const int n = blockIdx.x * WPB + (threadIdx.x >> 6);
    if (n >= N) return;

    float xv = in[(size_t)n * 64 + lane];
    float tv = fminf(fmaxf(xv, -1.f), 1.f) * 7.5f + 7.5f;
    int iv = (int)tv; iv = iv > 14 ? 14 : iv;
    float frv = tv - (float)iv;
    int offv = lane * 3840 + (iv << 8);   // uint rows: 256B; 15*256 per dim

    const char* tb = (const char*)tab + lane * 4;
    float acc0 = 0.f, acc1 = 0.f;
#pragma unroll
    for (int i0 = 0; i0 < 64; i0 += 8) {
        int of[8]; float fr[8]; unsigned int e[8];
#pragma unroll
        for (int j = 0; j < 8; ++j) of[j] = __shfl(offv, i0 + j, 64);
#pragma unroll
        for (int j = 0; j < 8; ++j) fr[j] = __shfl(frv, i0 + j, 64);
#pragma unroll
        for (int j = 0; j < 8; ++j) e[j] = *(const unsigned int*)(tb + of[j]);
#pragma unroll
        for (int j = 0; j < 8; j += 2) {
            acc0 += fmaf(fr[j], unpack_f16_hi(e[j]), unpack_f16_lo(e[j]));
            acc1 += fmaf(fr[j + 1], unpack_f16_hi(e[j + 1]), unpack_f16_lo(e[j + 1]));
        }
    }
    out[(size_t)n * 64 + lane] = acc0 + acc1;
}

// ---- scan pass 1: per-chunk affine summary (A, B): h_out = A*h_in + B ----
__global__ __launch_bounds__(256) void scan_pass1_kernel(
    const float2* __restrict__ zh, float2* __restrict__ chunkAB, int T)
{
    int lane = threadIdx.x & 63;
    int wid = blockIdx.x * (blockDim.x >> 6) + (threadIdx.x >> 6);  // b*NC + c
    int b = wid / NC, c = wid % NC;
    const float2* p = zh + ((size_t)b * T + (size_t)c * CL) * 64 + lane;

    float A = 1.f, Bc = 0.f;
    for (int k0 = 0; k0 < CL; k0 += 8) {
        float2 v[8];
#pragma unroll
        for (int k = 0; k < 8; ++k) v[k] = p[(size_t)(k0 + k) * 64];
#pragma unroll
        for (int k = 0; k < 8; ++k) {
            float a = 1.f - v[k].x;
            float bb = v[k].x * v[k].y;
            A *= a;
            Bc = fmaf(a, Bc, bb);
        }
    }
    chunkAB[(size_t)wid * 64 + lane] = make_float2(A, Bc);
}

// ---- scan fixup: sequential combine of NC chunk summaries per (b, d) ----
__global__ __launch_bounds__(64) void scan_fixup_kernel(
    const float2* __restrict__ chunkAB, float* __restrict__ hinit)
{
    int b = blockIdx.x;
    int d = threadIdx.x;
    const float2* p = chunkAB + (size_t)b * NC * 64 + d;
    float* o = hinit + (size_t)b * NC * 64 + d;

    float h = 0.f;  // h0 = 0
    for (int c0 = 0; c0 < NC; c0 += 8) {
        float2 ab[8];
#pragma unroll
        for (int k = 0; k < 8; ++k) ab[k] = p[(size_t)(c0 + k) * 64];
#pragma unroll
        for (int k = 0; k < 8; ++k) {
            o[(size_t)(c0 + k) * 64] = h;
            h = fmaf(ab[k].x, h, ab[k].y);
        }
    }
}

// ---- scan pass 2: replay chunk from hinit, fused maxabs-normalize ----
__global__ __launch_bounds__(256) void scan_pass2_kernel(
    const float2* __restrict__ zh, const float* __restrict__ hinit,
    float* __restrict__ out, int T)
{
    int lane = threadIdx.x & 63;
    int wid = blockIdx.x * (blockDim.x >> 6) + (threadIdx.x >> 6);  // b*NC + c
    int b = wid / NC, c = wid % NC;
    const float2* p = zh + ((size_t)b * T + (size_t)c * CL) * 64 + lane;
    float* o = out + ((size_t)b * T + (size_t)c * CL) * 64 + lane;

    float h = hinit[(size_t)wid * 64 + lane];
    for (int k0 = 0; k0 < CL; k0 += 8) {
        float2 v[8];
        float hs[8];
#pragma unroll
        for (int k = 0; k < 8; ++k) v[k] = p[(size_t)(k0 + k) * 64];
#pragma unroll
        for (int k = 0; k < 8; ++k) {
            h = fmaf(v[k].x, v[k].y - h, h);   // h += z*(hbar - h)
            hs[k] = h;
        }
#pragma unroll
        for (int k = 0; k < 8; ++k) {
            float m = fabsf(hs[k]);
            m = fmaxf(m, __shfl_xor(m, 32, 64));
            m = fmaxf(m, __shfl_xor(m, 16, 64));
            m = fmaxf(m, __shfl_xor(m, 8, 64));
            m = fmaxf(m, __shfl_xor(m, 4, 64));
            m = fmaxf(m, __shfl_xor(m, 2, 64));
            m = fmaxf(m, __shfl_xor(m, 1, 64));
            o[(size_t)(k0 + k) * 64] = hs[k] / (m + 1e-6f);
        }
    }
}

extern "C" void kernel_launch(void* const* d_in, const int* in_sizes, int n_in,
                              void* d_out, int out_size, void* d_ws, size_t ws_size,
                              hipStream_t stream) {
    const float* x    = (const float*)d_in[0];
    const float* vz0  = (const float*)d_in[1];
    const float* vh0  = (const float*)d_in[2];
    const float* vz1  = (const float*)d_in[3];
    const float* vh1  = (const float*)d_in[4];
    const float* vz2  = (const float*)d_in[5];
    const float* vh2  = (const float*)d_in[6];
    const float* vout = (const float*)d_in[7];

    const int N = in_sizes[0] / 64;   // B*T = 16384
    const int T = NC * CL;            // 2048
    const int B = N / T;              // 8

    char* ws = (char*)d_ws;
    const size_t TAB_ELEMS = (size_t)64 * 15 * 64;   // 61440
    float2* zh      = (float2*)ws;                                  // 8 MB
    float*  cur     = (float*)(ws + 8388608);                       // 4 MB
    float4* tab0    = (float4*)(ws + 12582912);                     // 960 KB
    float4* tab1    = (float4*)(ws + 13565952);                     // 960 KB
    float4* tab2    = (float4*)(ws + 14548992);                     // 960 KB
    unsigned int* tab_out = (unsigned int*)(ws + 15532032);         // 240 KB
    float2* chunkAB = (float2*)(ws + 16023552);                     // 256 KB
    float*  hinit   = (float*)(ws + 16285696);                      // 128 KB

    dim3 pblk(256), pgrd((TAB_ELEMS + 255) / 256);
    prep_dual_kernel<<<pgrd, pblk, 0, stream>>>(vz0, vh0, tab0);
    prep_dual_kernel<<<pgrd, pblk, 0, stream>>>(vz1, vh1, tab1);
    prep_dual_kernel<<<pgrd, pblk, 0, stream>>>(vz2, vh2, tab2);
    prep_out_kernel<<<pgrd, pblk, 0, stream>>>(vout, tab_out);

    dim3 lblk(512), lgrd(N / 64);            // 256 blocks of 512 threads
    dim3 ablk(64 * WPB), agrd((N + WPB - 1) / WPB);
    dim3 sblk(256), sgrd(B * NC / 4);        // 4 waves (chunks) per block

    const float4* tabs[3] = {tab0, tab1, tab2};
    const float* layer_in = x;
    for (int l = 0; l < 3; ++l) {
        apl_dual_lds_kernel<<<lgrd, lblk, 0, stream>>>(layer_in, tabs[l], zh);
        scan_pass1_kernel<<<sgrd, sblk, 0, stream>>>(zh, chunkAB, T);
        scan_fixup_kernel<<<B, 64, 0, stream>>>(chunkAB, hinit);
        scan_pass2_kernel<<<sgrd, sblk, 0, stream>>>(zh, hinit, cur, T);
        layer_in = cur;
    }
    apl_out_kernel<<<agrd, ablk, 0, stream>>>(cur, tab_out, (float*)d_out, N);
}

// Round 17
// 186.032 us; speedup vs baseline: 1.0974x; 1.0151x over previous
//
#include <hip/hip_runtime.h>
#include <hip/hip_fp16.h>

// MinGRU stack: 3x (APL z/h + linear recurrence + maxabs-normalize) + APL out.
// B=8, T=2048, Din=D=Dout=64, P=16 knots on [-1,1].
// Final best-merge of 16 rounds of measurement:
//  - Layers 1-2: LDS-staged AoS float4 slices, ONE ds_read_b128 per
//    sample-dim (fastest measured f32 path: ~38.5 us vs 41.4 direct gather).
//    Tables MUST stay f32 (round-10: bf16 z -> 2.37 absmax, ~600x amplif.).
//  - Layer 3: direct gather, full-f16 uint2 rows, ONE 8B load per iter
//    (~38.5 us; error amplified only ~21x by out layer -> +0.04, proven r14).
//  - Out layer: direct gather, f16x2 table (~11 us, proven r11+).
//  - Scan: pass1 / fixup / pass2 (r8 structure; fusions regressed in r9).
// Measured wall: dual-APL pinned ~40 us by vector-memory/LDS issue rate
// (L2 gather 41.4, LDS-b32 43.5, LDS-b128 38.5); byte cuts, ILP, occupancy,
// block shape all null (r7/r8/r9/r12/r14/r15/r16).

#define WPB 8   // waves per block in gather-APL kernels (512 threads)
#define NC 64   // chunks per sequence
#define CL 32   // timesteps per chunk (NC*CL == T == 2048)

__device__ __forceinline__ unsigned int pack_f16(float lo, float hi) {
    return (unsigned int)__half_as_ushort(__float2half(lo))
         | ((unsigned int)__half_as_ushort(__float2half(hi)) << 16);
}
__device__ __forceinline__ float unpack_f16_lo(unsigned int u) {
    return __half2float(__ushort_as_half((unsigned short)(u & 0xffffu)));
}
__device__ __forceinline__ float unpack_f16_hi(unsigned int u) {
    return __half2float(__ushort_as_half((unsigned short)(u >> 16)));
}

// ---- table prep (layers 1-2): float4(z0, dz, h0, dh), f32 ----
__global__ __launch_bounds__(256) void prep_dual_kernel(
    const float* __restrict__ vz, const float* __restrict__ vh,
    float4* __restrict__ tab)
{
    int idx = blockIdx.x * blockDim.x + threadIdx.x;   // over 64*15*64
    if (idx >= 64 * 15 * 64) return;
    int o = idx & 63;
    int p = (idx >> 6) % 15;
    int i = idx / (15 * 64);
    int base = (i * 16 + p) * 64 + o;
    float z0 = vz[base], z1 = vz[base + 64];
    float h0 = vh[base], h1 = vh[base + 64];
    tab[idx] = make_float4(z0, z1 - z0, h0, h1 - h0);
}

// ---- table prep (layer 3): uint2 = (f16 z0|dz, f16 h0|dh) ----
__global__ __launch_bounds__(256) void prep_dual_l3_kernel(
    const float* __restrict__ vz, const float* __restrict__ vh,
    uint2* __restrict__ tab)
{
    int idx = blockIdx.x * blockDim.x + threadIdx.x;
    if (idx >= 64 * 15 * 64) return;
    int o = idx & 63;
    int p = (idx >> 6) % 15;
    int i = idx / (15 * 64);
    int base = (i * 16 + p) * 64 + o;
    float z0 = vz[base], z1 = vz[base + 64];
    float h0 = vh[base], h1 = vh[base + 64];
    tab[idx] = make_uint2(pack_f16(z0, z1 - z0), pack_f16(h0, h1 - h0));
}

// output table: packed f16x2 (v0 low, dv high)
__global__ __launch_bounds__(256) void prep_out_kernel(
    const float* __restrict__ v, unsigned int* __restrict__ tab)
{
    int idx = blockIdx.x * blockDim.x + threadIdx.x;
    if (idx >= 64 * 15 * 64) return;
    int o = idx & 63;
    int p = (idx >> 6) % 15;
    int i = idx / (15 * 64);
    int base = (i * 16 + p) * 64 + o;
    float v0 = v[base], v1 = v[base + 64];
    tab[idx] = pack_f16(v0, v1 - v0);
}

// ---- APL dual, LDS-staged (AoS float4, b128 reads) — layers 1-2 ----
__global__ __launch_bounds__(512) void apl_dual_lds_kernel(
    const float* __restrict__ in, const float4* __restrict__ tab,
    float2* __restrict__ zh)
{
    __shared__ float4 slc[2][960];   // 30720 B double-buffered slice

    const int tid = threadIdx.x;
    const int lane = tid & 63;
    const int w = tid >> 6;
    const size_t nb = (size_t)blockIdx.x * 64 + (size_t)w * 8;  // wave's 8 samples

    int   iv8[8];
    float fr8[8];
#pragma unroll
    for (int s = 0; s < 8; ++s) {
        float xv = in[(nb + s) * 64 + lane];
        float tv = fminf(fmaxf(xv, -1.f), 1.f) * 7.5f + 7.5f;   // [0,15]
        int iv = (int)tv; iv = iv > 14 ? 14 : iv;
        iv8[s] = iv;
        fr8[s] = tv - (float)iv;
    }

    float accz[8], acch[8];
#pragma unroll
    for (int s = 0; s < 8; ++s) { accz[s] = 0.f; acch[s] = 0.f; }

    // prologue: prefetch slice 0 into registers
    float4 e0 = tab[tid];
    float4 e1 = make_float4(0.f, 0.f, 0.f, 0.f);
    if (tid < 448) e1 = tab[tid + 512];

#pragma unroll 2
    for (int i = 0; i < 64; ++i) {
        const int buf = i & 1;
        slc[buf][tid] = e0;
        if (tid < 448) slc[buf][tid + 512] = e1;
        if (i < 63) {
            const float4* src = tab + (size_t)(i + 1) * 960;
            e0 = src[tid];
            if (tid < 448) e1 = src[tid + 512];
        }
        __syncthreads();
#pragma unroll
        for (int s = 0; s < 8; ++s) {
            int idx  = __builtin_amdgcn_readlane(iv8[s], i);
            float fr = __int_as_float(
                __builtin_amdgcn_readlane(__float_as_int(fr8[s]), i));
            float4 e = slc[buf][idx * 64 + lane];   // contiguous 1KB row
            accz[s] += fmaf(fr, e.y, e.x);
            acch[s] += fmaf(fr, e.w, e.z);
        }
    }

#pragma unroll
    for (int s = 0; s < 8; ++s) {
        float z = 1.f / (1.f + expf(-accz[s]));
        zh[(nb + s) * 64 + lane] = make_float2(z, acch[s]);
    }
}

// ---- APL dual, layer 3: direct gather, full-f16 uint2 rows, one 8B load ----
__global__ __launch_bounds__(512) void apl_dual_l3_kernel(
    const float* __restrict__ in, const uint2* __restrict__ tab,
    float2* __restrict__ zh, int N)
{
    const int lane = threadIdx.x & 63;
    const int n = blockIdx.x * WPB + (threadIdx.x >> 6);
    if (n >= N) return;

    float xv = in[(size_t)n * 64 + lane];
    float tv = fminf(fmaxf(xv, -1.f), 1.f) * 7.5f + 7.5f;
    int iv = (int)tv; iv = iv > 14 ? 14 : iv;
    float frv = tv - (float)iv;
    int offv = lane * 7680 + (iv << 9);   // uint2 rows: 512B; 15*512 per dim

    const char* tb = (const char*)tab + lane * 8;
    float accz0 = 0.f, acch0 = 0.f, accz1 = 0.f, acch1 = 0.f;
#pragma unroll
    for (int i0 = 0; i0 < 64; i0 += 4) {
        int of0 = __shfl(offv, i0 + 0, 64);
        int of1 = __shfl(offv, i0 + 1, 64);
        int of2 = __shfl(offv, i0 + 2, 64);
        int of3 = __shfl(offv, i0 + 3, 64);
        float fr0 = __shfl(frv, i0 + 0, 64);
        float fr1 = __shfl(frv, i0 + 1, 64);
        float fr2 = __shfl(frv, i0 + 2, 64);
        float fr3 = __shfl(frv, i0 + 3, 64);
        uint2 e0 = *(const uint2*)(tb + of0);
        uint2 e1 = *(const uint2*)(tb + of1);
        uint2 e2 = *(const uint2*)(tb + of2);
        uint2 e3 = *(const uint2*)(tb + of3);
        accz0 += fmaf(fr0, unpack_f16_hi(e0.x), unpack_f16_lo(e0.x));
        acch0 += fmaf(fr0, unpack_f16_hi(e0.y), unpack_f16_lo(e0.y));
        accz1 += fmaf(fr1, unpack_f16_hi(e1.x), unpack_f16_lo(e1.x));
        acch1 += fmaf(fr1, unpack_f16_hi(e1.y), unpack_f16_lo(e1.y));
        accz0 += fmaf(fr2, unpack_f16_hi(e2.x), unpack_f16_lo(e2.x));
        acch0 += fmaf(fr2, unpack_f16_hi(e2.y), unpack_f16_lo(e2.y));
        accz1 += fmaf(fr3, unpack_f16_hi(e3.x), unpack_f16_lo(e3.x));
        acch1 += fmaf(fr3, unpack_f16_hi(e3.y), unpack_f16_lo(e3.y));
    }
    float accz = accz0 + accz1, acch = acch0 + acch1;
    float z = 1.f / (1.f + expf(-accz));
    zh[(size_t)n * 64 + lane] = make_float2(z, acch);
}

// ---- APL (f16x2 table, output layer), direct gather, 8-deep batching ----
__global__ __launch_bounds__(512) void apl_out_kernel(
    const float* __restrict__ in, const unsigned int* __restrict__ tab,
    float* __restrict__ out, int N)
{
    const int lane = threadIdx.x & 63;
    const int n = blockIdx.x * WPB + (threadIdx.x >> 6);
    if (n >= N) return;

    float xv = in[(size_t)n * 64 + lane];
    float tv = fminf(fmaxf(xv, -1.f), 1.f) * 7.5f + 7.5f;
    int iv = (int)tv; iv = iv > 14 ? 14 : iv;
    float frv = tv - (float)iv;
    int offv = lane * 3840 + (iv << 8);   // uint rows: 256B; 15*256 per dim

    const char* tb = (const char*)tab + lane * 4;
    float acc0 = 0.f, acc1 = 0.f;
#pragma unroll
    for (int i0 = 0; i0 < 64; i0 += 8) {
        int of[8]; float fr[8]; unsigned int e[8];
#pragma unroll
        for (int j = 0; j < 8; ++j) of[j] = __shfl(offv, i0 + j, 64);
#pragma unroll
        for (int j = 0; j < 8; ++j) fr[j] = __shfl(frv, i0 + j, 64);
#pragma unroll
        for (int j = 0; j < 8; ++j) e[j] = *(const unsigned int*)(tb + of[j]);
#pragma unroll
        for (int j = 0; j < 8; j += 2) {
            acc0 += fmaf(fr[j], unpack_f16_hi(e[j]), unpack_f16_lo(e[j]));
            acc1 += fmaf(fr[j + 1], unpack_f16_hi(e[j + 1]), unpack_f16_lo(e[j + 1]));
        }
    }
    out[(size_t)n * 64 + lane] = acc0 + acc1;
}

// ---- scan pass 1: per-chunk affine summary (A, B): h_out = A*h_in + B ----
__global__ __launch_bounds__(256) void scan_pass1_kernel(
    const float2* __restrict__ zh, float2* __restrict__ chunkAB, int T)
{
    int lane = threadIdx.x & 63;
    int wid = blockIdx.x * (blockDim.x >> 6) + (threadIdx.x >> 6);  // b*NC + c
    int b = wid / NC, c = wid % NC;
    const float2* p = zh + ((size_t)b * T + (size_t)c * CL) * 64 + lane;

    float A = 1.f, Bc = 0.f;
    for (int k0 = 0; k0 < CL; k0 += 8) {
        float2 v[8];
#pragma unroll
        for (int k = 0; k < 8; ++k) v[k] = p[(size_t)(k0 + k) * 64];
#pragma unroll
        for (int k = 0; k < 8; ++k) {
            float a = 1.f - v[k].x;
            float bb = v[k].x * v[k].y;
            A *= a;
            Bc = fmaf(a, Bc, bb);
        }
    }
    chunkAB[(size_t)wid * 64 + lane] = make_float2(A, Bc);
}

// ---- scan fixup: sequential combine of NC chunk summaries per (b, d) ----
__global__ __launch_bounds__(64) void scan_fixup_kernel(
    const float2* __restrict__ chunkAB, float* __restrict__ hinit)
{
    int b = blockIdx.x;
    int d = threadIdx.x;
    const float2* p = chunkAB + (size_t)b * NC * 64 + d;
    float* o = hinit + (size_t)b * NC * 64 + d;

    float h = 0.f;  // h0 = 0
    for (int c0 = 0; c0 < NC; c0 += 8) {
        float2 ab[8];
#pragma unroll
        for (int k = 0; k < 8; ++k) ab[k] = p[(size_t)(c0 + k) * 64];
#pragma unroll
        for (int k = 0; k < 8; ++k) {
            o[(size_t)(c0 + k) * 64] = h;
            h = fmaf(ab[k].x, h, ab[k].y);
        }
    }
}

// ---- scan pass 2: replay chunk from hinit, fused maxabs-normalize ----
__global__ __launch_bounds__(256) void scan_pass2_kernel(
    const float2* __restrict__ zh, const float* __restrict__ hinit,
    float* __restrict__ out, int T)
{
    int lane = threadIdx.x & 63;
    int wid = blockIdx.x * (blockDim.x >> 6) + (threadIdx.x >> 6);  // b*NC + c
    int b = wid / NC, c = wid % NC;
    const float2* p = zh + ((size_t)b * T + (size_t)c * CL) * 64 + lane;
    float* o = out + ((size_t)b * T + (size_t)c * CL) * 64 + lane;

    float h = hinit[(size_t)wid * 64 + lane];
    for (int k0 = 0; k0 < CL; k0 += 8) {
        float2 v[8];
        float hs[8];
#pragma unroll
        for (int k = 0; k < 8; ++k) v[k] = p[(size_t)(k0 + k) * 64];
#pragma unroll
        for (int k = 0; k < 8; ++k) {
            h = fmaf(v[k].x, v[k].y - h, h);   // h += z*(hbar - h)
            hs[k] = h;
        }
#pragma unroll
        for (int k = 0; k < 8; ++k) {
            float m = fabsf(hs[k]);
            m = fmaxf(m, __shfl_xor(m, 32, 64));
            m = fmaxf(m, __shfl_xor(m, 16, 64));
            m = fmaxf(m, __shfl_xor(m, 8, 64));
            m = fmaxf(m, __shfl_xor(m, 4, 64));
            m = fmaxf(m, __shfl_xor(m, 2, 64));
            m = fmaxf(m, __shfl_xor(m, 1, 64));
            o[(size_t)(k0 + k) * 64] = hs[k] / (m + 1e-6f);
        }
    }
}

extern "C" void kernel_launch(void* const* d_in, const int* in_sizes, int n_in,
                              void* d_out, int out_size, void* d_ws, size_t ws_size,
                              hipStream_t stream) {
    const float* x    = (const float*)d_in[0];
    const float* vz0  = (const float*)d_in[1];
    const float* vh0  = (const float*)d_in[2];
    const float* vz1  = (const float*)d_in[3];
    const float* vh1  = (const float*)d_in[4];
    const float* vz2  = (const float*)d_in[5];
    const float* vh2  = (const float*)d_in[6];
    const float* vout = (const float*)d_in[7];

    const int N = in_sizes[0] / 64;   // B*T = 16384
    const int T = NC * CL;            // 2048
    const int B = N / T;              // 8

    char* ws = (char*)d_ws;
    const size_t TAB_ELEMS = (size_t)64 * 15 * 64;   // 61440
    float2* zh      = (float2*)ws;                                  // 8 MB
    float*  cur     = (float*)(ws + 8388608);                       // 4 MB
    float4* tab0    = (float4*)(ws + 12582912);                     // 960 KB
    float4* tab1    = (float4*)(ws + 13565952);                     // 960 KB
    uint2*  tab2    = (uint2*)(ws + 14548992);                      // 480 KB
    unsigned int* tab_out = (unsigned int*)(ws + 15040512);         // 240 KB
    float2* chunkAB = (float2*)(ws + 15286272);                     // 256 KB
    float*  hinit   = (float*)(ws + 15548416);                      // 128 KB

    dim3 pblk(256), pgrd((TAB_ELEMS + 255) / 256);
    prep_dual_kernel<<<pgrd, pblk, 0, stream>>>(vz0, vh0, tab0);
    prep_dual_kernel<<<pgrd, pblk, 0, stream>>>(vz1, vh1, tab1);
    prep_dual_l3_kernel<<<pgrd, pblk, 0, stream>>>(vz2, vh2, tab2);
    prep_out_kernel<<<pgrd, pblk, 0, stream>>>(vout, tab_out);

    dim3 lblk(512), lgrd(N / 64);            // 256 blocks of 512 threads
    dim3 ablk(64 * WPB), agrd((N + WPB - 1) / WPB);
    dim3 sblk(256), sgrd(B * NC / 4);        // 4 waves (chunks) per block

    const float* layer_in = x;
    for (int l = 0; l < 3; ++l) {
        if (l < 2) {
            const float4* tab = (l == 0) ? tab0 : tab1;
            apl_dual_lds_kernel<<<lgrd, lblk, 0, stream>>>(layer_in, tab, zh);
        } else {
            apl_dual_l3_kernel<<<agrd, ablk, 0, stream>>>(layer_in, tab2, zh, N);
        }
        scan_pass1_kernel<<<sgrd, sblk, 0, stream>>>(zh, chunkAB, T);
        scan_fixup_kernel<<<B, 64, 0, stream>>>(chunkAB, hinit);
        scan_pass2_kernel<<<sgrd, sblk, 0, stream>>>(zh, hinit, cur, T);
        layer_in = cur;
    }
    apl_out_kernel<<<agrd, ablk, 0, stream>>>(cur, tab_out, (float*)d_out, N);
}